// Round 4
// baseline (208.356 us; speedup 1.0000x reference)
//
#include <hip/hip_runtime.h>

// SpectralConv2d DHT spectral conv, B=16, Cin=Cout=64, H=W=128, modes 20x20.
// All stages linear; blurs folded into bases/weights.
//   fwd:  X(k1,k2) = sum_n1 [cos(th k1 n1) Pc - sin(th k1 n1) Ps
//                            - sin(th k1(n1+1)) Pc1 - cos(th k1(n1+1)) Ps1]
//        rotation folded:  X1 = D0 + D1 + ck*(D2c+D3s) + sk*(D3c-D2s)
//   inv (rank-42): y(u,v) = sum_{A=0..20} cosb(u,A)*RsC[A][v] + sinb(u,A)*RsS[A][v]
// Kernels (4 launches):
//  kA (451 blocks): blk0-2 = init tables (L2g/RB2g, Tg, Lf2g); blk3+ = w1 blur+T
//  k12 v5: per (b,c), 320 thr. Async-STAGE pipeline (next-chunk regs prefetched
//       during GEMM), 64-n2 chunks (4 barriers in main loop), s_load B-operand.
//  k3 v4: m-major (400 blocks): blur once for 16 b, weights reused x4 b.
//  k5b v3: masked-v exploited: waves 0-1 compute v0..31, waves 2-3 v96..127
//       (wave-uniform, stores coalesced); v=32 column pass; zero-fill v33..95;
//       Rs built only for live vq groups (0..8, 24..31).

#define TWO_PI 6.283185307179586f
#define THETA (TWO_PI / 128.0f)

__device__ __forceinline__ void gauss9(float* g) {
  float s = 0.f;
#pragma unroll
  for (int t = 0; t < 9; ++t) { float d = (float)(t - 4); g[t] = expf(-0.5f * d * d); s += g[t]; }
  float inv = 1.f / s;
#pragma unroll
  for (int t = 0; t < 9; ++t) g[t] *= inv;
}

// ---- kA: blk0: L2g+RB2g (42x128), blk1: Tg, blk2: Lf2g, blk3..450: w1 blur+T
__global__ void kA_init(float* __restrict__ L2g, float* __restrict__ RB2g,
                        float* __restrict__ Tg, float* __restrict__ Lf2g,
                        const float* __restrict__ w1, float* __restrict__ wbT) {
  __shared__ float sh[5632];   // raw[128][44] (blk0) | tile[64][69] (blk>=3)
  int tid = threadIdx.x;
  int blk = blockIdx.x;
  if (blk == 1) {
    for (int i = tid; i < 5120; i += 256) {
      int n2 = i / 40, col = i - n2 * 40;
      int k2 = (col < 20) ? col : col - 20;
      float a = (float)((k2 * n2) & 127) * THETA;
      Tg[i] = (col < 20) ? cosf(a) : sinf(a);
    }
    return;
  }
  if (blk == 2) {
    for (int i = tid; i < 10240; i += 256) {
      int k1 = i >> 9, t = i & 511;
      int q = t >> 7, n1 = t & 127;
      int nn = n1 + ((q >= 2) ? 1 : 0);
      float a = (float)((k1 * nn) & 127) * THETA;
      float v;
      if (q == 0) v = cosf(a);
      else if (q == 1) v = -sinf(a);
      else if (q == 2) v = -sinf(a);
      else v = -cosf(a);
      Lf2g[i] = v;
    }
    return;
  }
  if (blk == 0) {
    // rank-42 bases. rows 0..20 = cos(th u A), 21..41 = sin(th u A)
    for (int i = tid; i < 5376; i += 256) {
      int u = i / 42, t = i - u * 42;
      int A = (t < 21) ? t : t - 21;
      float a = (float)((u * A) & 127) * THETA;
      sh[u * 44 + t] = (t < 21) ? cosf(a) : sinf(a);
    }
    __syncthreads();
    float g[9]; gauss9(g);
    for (int i = tid; i < 5376; i += 256) {
      int u = i / 42, t = i - u * 42;
      float acc = 0.f;
#pragma unroll
      for (int tp = 0; tp < 9; ++tp) {
        int uc = u - 4 + tp; uc = uc < 0 ? 0 : (uc > 127 ? 127 : uc);
        acc += g[tp] * sh[uc * 44 + t];
      }
      L2g[t * 128 + u] = acc;
      bool keep = (u <= 32) || (u >= 96);
      RB2g[t * 128 + u] = keep ? acc : 0.f;
    }
    return;
  }
  // blk >= 3: blur w1 over Cout + transpose: wbT[(c*400+m)*64+o]
  int bb = blk - 3;
  int c = bb / 7, chunk = bb % 7;
  int m0 = chunk * 64;
  int mw = 400 - m0; if (mw > 64) mw = 64;
  for (int t = tid; t < 4096; t += 256) {
    int o = t >> 6, mm = t & 63;
    sh[o * 69 + mm] = (mm < mw) ? w1[(c * 64 + o) * 400 + m0 + mm] : 0.f;
  }
  __syncthreads();
  float g[9]; gauss9(g);
  for (int t = tid; t < 4096; t += 256) {
    int mm = t >> 6, o = t & 63;
    if (mm >= mw) continue;
    float acc = 0.f;
#pragma unroll
    for (int tp = 0; tp < 9; ++tp) {
      int oc = o - 4 + tp; oc = oc < 0 ? 0 : (oc > 63 ? 63 : oc);
      acc += g[tp] * sh[oc * 69 + mm];
    }
    wbT[(c * 400 + m0 + mm) * 64 + o] = acc;
  }
}

// ---- k12 v5: fused forward transform + mode combine. One block per (b,c).
// 320 threads = 5 waves; wave w owns cols 8w..8w+7, lane L owns rows 2L,2L+1.
// B-operand: Tg slice via wave-uniform pointer -> s_load (no LDS traffic).
// Staging: 2 chunks of 64 n2; next chunk prefetched into pv[7] registers
// BEFORE the current GEMM (async-STAGE, statically indexed unroll).
// LDS: xs[64][132] = 33792 B (phase 1) overlaps Pm2[20][256] (phase 2).
__global__ void __launch_bounds__(320, 5) k12(const float* __restrict__ x,
                                              const float* __restrict__ Tg,
                                              const float* __restrict__ Lf2g,
                                              float* __restrict__ X1) {
  __shared__ float lds[8448];   // 33792 B
  int bc = blockIdx.x, tid = threadIdx.x;
  int w = __builtin_amdgcn_readfirstlane(tid >> 6);   // wave id 0..4 (uniform)
  int L = tid & 63;
  const float* xb = x + (long)bc * 16384;
  const float* tgw = Tg + w * 8;                      // wave-uniform base

  float acc[2][8];
#pragma unroll
  for (int i = 0; i < 2; ++i)
#pragma unroll
    for (int j = 0; j < 8; ++j) acc[i][j] = 0.f;

  // prefetch registers: 2048 tasks / 320 threads -> up to 7 tasks (tid<128: 7)
  float4 pv[7];
  // load chunk 0
#pragma unroll
  for (int i = 0; i < 7; ++i) {
    int t = tid + 320 * i;
    if (t < 2048) {
      int n2l = t & 63, n1g = t >> 6;
      const float* gp = xb + n1g * 512 + n2l;
      pv[i] = make_float4(gp[0], gp[128], gp[256], gp[384]);
    }
  }
  for (int ch = 0; ch < 2; ++ch) {
    __syncthreads();                 // prior GEMM done reading xs
    // write staged regs to LDS (b128, conflict-free: chunk 33*n2l+n1g)
#pragma unroll
    for (int i = 0; i < 7; ++i) {
      int t = tid + 320 * i;
      if (t < 2048) {
        int n2l = t & 63, n1g = t >> 6;
        *(float4*)&lds[n2l * 132 + n1g * 4] = pv[i];
      }
    }
    if (ch == 0) {
      // issue next chunk's global loads (in flight across the GEMM)
#pragma unroll
      for (int i = 0; i < 7; ++i) {
        int t = tid + 320 * i;
        if (t < 2048) {
          int n2l = t & 63, n1g = t >> 6;
          const float* gp = xb + n1g * 512 + 64 + n2l;
          pv[i] = make_float4(gp[0], gp[128], gp[256], gp[384]);
        }
      }
    }
    __syncthreads();                 // xs ready
#pragma unroll 4
    for (int k = 0; k < 64; ++k) {
      float2 av = *(const float2*)&lds[k * 132 + 2 * L];     // rows 2L,2L+1
      const float* tr = tgw + (ch * 64 + k) * 40;            // uniform -> s_load
      float4 b0 = *(const float4*)tr;
      float4 b1 = *(const float4*)(tr + 4);
      float bv[8] = {b0.x, b0.y, b0.z, b0.w, b1.x, b1.y, b1.z, b1.w};
#pragma unroll
      for (int j = 0; j < 8; ++j) {
        acc[0][j] += av.x * bv[j];
        acc[1][j] += av.y * bv[j];
      }
    }
  }
  __syncthreads();
  // scatter into Pm2[20][256]: [0..128) Pc, [128..256) Ps; XOR swz (k2&7)<<2
#pragma unroll
  for (int j = 0; j < 8; ++j) {
    int col = w * 8 + j;
    int k2 = (col < 20) ? col : col - 20;
    int part = (col < 20) ? 0 : 128;
    int m = (k2 & 7) << 2;
    *(float2*)&lds[k2 * 256 + ((part + 2 * L) ^ m)] =
        make_float2(acc[0][j], acc[1][j]);
  }
  __syncthreads();
  // combine: 200 threads, 2 outputs (k2, k2+1) each; 6 separable dots
  if (tid < 200) {
    int k1 = tid / 10, k2 = (tid % 10) * 2;
    int m0 = (k2 & 7) << 2, m1 = ((k2 + 1) & 7) << 2;
    const float* lrow = Lf2g + k1 * 512;
    const float* p0 = lds + k2 * 256;
    const float* p1 = lds + (k2 + 1) * 256;
    float d0a = 0.f, d1a = 0.f, d2ca = 0.f, d2sa = 0.f, d3ca = 0.f, d3sa = 0.f;
    float d0b = 0.f, d1b = 0.f, d2cb = 0.f, d2sb = 0.f, d3cb = 0.f, d3sb = 0.f;
    for (int t = 0; t < 128; t += 4) {
      float4 l0 = *(const float4*)(lrow + t);
      float4 l1 = *(const float4*)(lrow + 128 + t);
      float4 l2 = *(const float4*)(lrow + 256 + t);
      float4 l3 = *(const float4*)(lrow + 384 + t);
      float4 pc0 = *(const float4*)(p0 + (t ^ m0));
      float4 ps0 = *(const float4*)(p0 + ((128 + t) ^ m0));
      float4 pc1 = *(const float4*)(p1 + (t ^ m1));
      float4 ps1 = *(const float4*)(p1 + ((128 + t) ^ m1));
      d0a += l0.x*pc0.x + l0.y*pc0.y + l0.z*pc0.z + l0.w*pc0.w;
      d1a += l1.x*ps0.x + l1.y*ps0.y + l1.z*ps0.z + l1.w*ps0.w;
      d2ca += l2.x*pc0.x + l2.y*pc0.y + l2.z*pc0.z + l2.w*pc0.w;
      d2sa += l2.x*ps0.x + l2.y*ps0.y + l2.z*ps0.z + l2.w*ps0.w;
      d3ca += l3.x*pc0.x + l3.y*pc0.y + l3.z*pc0.z + l3.w*pc0.w;
      d3sa += l3.x*ps0.x + l3.y*ps0.y + l3.z*ps0.z + l3.w*ps0.w;
      d0b += l0.x*pc1.x + l0.y*pc1.y + l0.z*pc1.z + l0.w*pc1.w;
      d1b += l1.x*ps1.x + l1.y*ps1.y + l1.z*ps1.z + l1.w*ps1.w;
      d2cb += l2.x*pc1.x + l2.y*pc1.y + l2.z*pc1.z + l2.w*pc1.w;
      d2sb += l2.x*ps1.x + l2.y*ps1.y + l2.z*ps1.z + l2.w*ps1.w;
      d3cb += l3.x*pc1.x + l3.y*pc1.y + l3.z*pc1.z + l3.w*pc1.w;
      d3sb += l3.x*ps1.x + l3.y*ps1.y + l3.z*ps1.z + l3.w*ps1.w;
    }
    float ska, cka, skb, ckb;
    sincosf(THETA * (float)k2, &ska, &cka);
    sincosf(THETA * (float)(k2 + 1), &skb, &ckb);
    X1[(k1 * 20 + k2) * 1024 + bc] = d0a + d1a + cka * (d2ca + d3sa) + ska * (d3ca - d2sa);
    X1[(k1 * 20 + k2 + 1) * 1024 + bc] = d0b + d1b + ckb * (d2cb + d3sb) + skb * (d3cb - d2sb);
  }
}

// ---- k3 v4: m-major. One block per m (400 blocks). O[(b*64+o)*400+m]
// Blur over b once for all 16 b; each weight load reused for 4 b outputs.
// acc[b] = sum_c wbT[c,m,o]*sc*(Xa+Xn)[b,c] + wbT[c,nm,o]*sc*(Xa-Xn)[b,c]
__global__ void k3_mix(const float* __restrict__ X1, const float* __restrict__ wbT,
                       float* __restrict__ O) {
  __shared__ float Xp[16][64], Xm[16][64];
  int m = blockIdx.x;
  int i = m / 20, j = m - i * 20;
  int nm = ((20 - i) % 20) * 20 + ((20 - j) % 20);
  int tid = threadIdx.x;
  const float sc = 0.5f / 16384.0f;
  float g[9]; gauss9(g);
  {
    int bl = tid >> 6, c = tid & 63;
#pragma unroll
    for (int it = 0; it < 4; ++it) {
      int b = bl * 4 + it;
      float sa = 0.f, sn = 0.f;
#pragma unroll
      for (int tp = 0; tp < 9; ++tp) {
        int bb = b - 4 + tp; bb = bb < 0 ? 0 : (bb > 15 ? 15 : bb);
        sa += g[tp] * X1[m * 1024 + bb * 64 + c];
        sn += g[tp] * X1[nm * 1024 + bb * 64 + c];
      }
      Xp[b][c] = (sa + sn) * sc; Xm[b][c] = (sa - sn) * sc;
    }
  }
  __syncthreads();
  int o = tid & 63, bq = tid >> 6;   // wave-uniform bq -> LDS broadcast reads
  float acc[4] = {0.f, 0.f, 0.f, 0.f};
#pragma unroll 4
  for (int c = 0; c < 64; ++c) {
    float wp = wbT[(c * 400 + m) * 64 + o];
    float wm = wbT[(c * 400 + nm) * 64 + o];
#pragma unroll
    for (int k = 0; k < 4; ++k)
      acc[k] += Xp[bq * 4 + k][c] * wp + Xm[bq * 4 + k][c] * wm;
  }
#pragma unroll
  for (int k = 0; k < 4; ++k)
    O[((bq * 4 + k) * 64 + o) * 400 + m] = acc[k];
}

// ---- k5b v3: per (b,o). Only v in [0,32] u [96,127] is nonzero (RB2g mask).
// Rs built for live vq groups only (0..8, 24..31). Final GEMM: waves 0-1
// compute v 0..31, waves 2-3 compute v 96..127 (wave-uniform, coalesced
// stores); v=32 column via 128-thread pass; v 33..95 zero-filled.
__global__ void __launch_bounds__(256) k5b_final(const float* __restrict__ O,
                                                 const float* __restrict__ L2g,
                                                 const float* __restrict__ RB2g,
                                                 float* __restrict__ out) {
  __shared__ float Os[400];
  __shared__ float Rs[42 * 128];
  int bo = blockIdx.x, tid = threadIdx.x;
  for (int t = tid; t < 400; t += 256) Os[t] = O[bo * 400 + t];
  __syncthreads();
  const float4* Bc4 = (const float4*)RB2g;             // rows 0..20
  const float4* Bs4 = (const float4*)(RB2g + 21 * 128);
  {
    int rg = tid & 7;                 // row-group (rg<7: rows 6rg..6rg+5)
    int vqIdx = tid >> 3;             // 0..31; live for vqIdx<17
    int vq = (vqIdx < 9) ? vqIdx : vqIdx + 15;   // 0..8, 24..31
    if (rg < 7 && vqIdx < 17) {
      int r0 = rg * 6;
      float4 a[6];
#pragma unroll
      for (int q = 0; q < 6; ++q) a[q] = make_float4(0.f, 0.f, 0.f, 0.f);
      for (int k2 = 0; k2 <= 20; ++k2) {
        float4 bc = Bc4[k2 * 32 + vq];
        float4 bs = Bs4[k2 * 32 + vq];
#pragma unroll
        for (int q = 0; q < 6; ++q) {
          int r = r0 + q;
          bool isS = (r >= 21);
          int A = isS ? (r - 21) : r;
          if (k2 < 20 && A < 20) {
            float ov = Os[A * 20 + k2];
            const float4 b = isS ? bs : bc;
            float s = isS ? -ov : ov;
            a[q].x += s * b.x; a[q].y += s * b.y; a[q].z += s * b.z; a[q].w += s * b.w;
          }
          if (k2 >= 1 && A >= 1) {
            float ov = Os[(A - 1) * 20 + (k2 - 1)];
            const float4 b = isS ? bc : bs;
            a[q].x -= ov * b.x; a[q].y -= ov * b.y; a[q].z -= ov * b.z; a[q].w -= ov * b.w;
          }
        }
      }
#pragma unroll
      for (int q = 0; q < 6; ++q)
        *(float4*)&Rs[(r0 + q) * 128 + vq * 4] = a[q];
    }
  }
  __syncthreads();
  long base = (long)bo * 16384;
  // main GEMM: half 0 (waves 0-1): v 0..31; half 1 (waves 2-3): v 96..127
  {
    int half = tid >> 7;
    int uu = (tid >> 3) & 15;  int u0 = uu * 8;
    int vv = tid & 7;          int v0 = half ? (96 + vv * 4) : vv * 4;
    float acc[8][4];
#pragma unroll
    for (int a = 0; a < 8; ++a)
#pragma unroll
      for (int b = 0; b < 4; ++b) acc[a][b] = 0.f;
    for (int r = 0; r < 42; ++r) {
      float4 a0 = *(const float4*)(L2g + r * 128 + u0);
      float4 a1 = *(const float4*)(L2g + r * 128 + u0 + 4);
      float4 b0 = *(const float4*)&Rs[r * 128 + v0];
      float av[8] = {a0.x, a0.y, a0.z, a0.w, a1.x, a1.y, a1.z, a1.w};
      float bv[4] = {b0.x, b0.y, b0.z, b0.w};
#pragma unroll
      for (int a = 0; a < 8; ++a)
#pragma unroll
        for (int b = 0; b < 4; ++b) acc[a][b] += av[a] * bv[b];
    }
#pragma unroll
    for (int a = 0; a < 8; ++a)
      *(float4*)&out[base + (u0 + a) * 128 + v0] =
          make_float4(acc[a][0], acc[a][1], acc[a][2], acc[a][3]);
  }
  // v = 32 column (only nonzero col in vq group 8)
  if (tid < 128) {
    float d = 0.f;
    for (int r = 0; r < 42; ++r) d += L2g[r * 128 + tid] * Rs[r * 128 + 32];
    out[base + tid * 128 + 32] = d;
  }
  // zero-fill v 33..95: per u, scalars 33-35 + float4 at 36..92
  float4 z4 = make_float4(0.f, 0.f, 0.f, 0.f);
  for (int jj = tid; jj < 2048; jj += 256) {
    int u = jj >> 4, s = jj & 15;
    long p = base + (long)u * 128;
    if (s == 15) { out[p + 33] = 0.f; out[p + 34] = 0.f; out[p + 35] = 0.f; }
    else *(float4*)&out[p + 36 + 4 * s] = z4;
  }
}

extern "C" void kernel_launch(void* const* d_in, const int* in_sizes, int n_in,
                              void* d_out, int out_size, void* d_ws, size_t ws_size,
                              hipStream_t stream) {
  const float* x = (const float*)d_in[0];    // (16,64,128,128)
  const float* w1 = (const float*)d_in[1];   // (64,64,20,20)
  float* out = (float*)d_out;                // (16,64,128,128)
  float* ws = (float*)d_ws;

  float* X1 = ws;                  // 409,600
  float* O = X1 + 409600;          // 409,600
  float* wbT = O + 409600;         // 1,638,400
  float* Tg = wbT + 1638400;       // 5,120
  float* Lf2g = Tg + 5120;         // 10,240
  float* L2g = Lf2g + 10240;       // 5,376
  float* RB2g = L2g + 5376;        // 5,376   (total ~10 MB)

  hipLaunchKernelGGL(kA_init, dim3(451), dim3(256), 0, stream,
                     L2g, RB2g, Tg, Lf2g, w1, wbT);
  hipLaunchKernelGGL(k12, dim3(1024), dim3(320), 0, stream, x, Tg, Lf2g, X1);
  hipLaunchKernelGGL(k3_mix, dim3(400), dim3(256), 0, stream, X1, wbT, O);
  hipLaunchKernelGGL(k5b_final, dim3(1024), dim3(256), 0, stream, O, L2g, RB2g, out);
}